// Round 2
// baseline (767.460 us; speedup 1.0000x reference)
//
#include <hip/hip_runtime.h>
#include <math.h>

#define NN 100000
#define NE 3200000
#define INF_ 128
#define D 32
#define H 4
#define HD 8

// binning config: bucket = dst >> 10 (monotonic in dst => bucket base = rs[b<<10])
#define NBKT 98                 // ceil(100000/1024)
#define NBLK 128                // chunking blocks for passes A/C
#define EPB (NE / NBLK)         // 25000 edges per block
#define DSPLIT 4                // sub-blocks per bucket in pass D

__device__ __forceinline__ float gelu_f(float x) {
    return 0.5f * x * (1.0f + erff(x * 0.70710678118654752f));
}

// h = gelu(x @ W_in + b_in); block = 256 threads = 8 nodes x 32 cols
__global__ __launch_bounds__(256) void k_in_proj(const float* __restrict__ x,
        const float* __restrict__ W, const float* __restrict__ b,
        float* __restrict__ h) {
    __shared__ float Ws[INF_ * D];     // 16 KB
    __shared__ float xs[8][INF_];      // 4 KB
    for (int i = threadIdx.x; i < INF_ * D; i += 256) Ws[i] = W[i];
    int ln = threadIdx.x >> 5;
    int col = threadIdx.x & 31;
    int node = blockIdx.x * 8 + ln;    // NN/8 = 12500 exact
    const float4* xr = (const float4*)(x + (size_t)node * INF_);
    ((float4*)xs[ln])[col] = xr[col];
    __syncthreads();
    float acc = b[col];
    #pragma unroll 16
    for (int i = 0; i < INF_; ++i) acc = fmaf(xs[ln][i], Ws[i * D + col], acc);
    h[(size_t)node * D + col] = gelu_f(acc);
}

// q,k,v = h @ {Wq,Wk,Wv} + bias; 8 nodes per block
__global__ __launch_bounds__(256) void k_qkv(const float* __restrict__ h,
        const float* __restrict__ Wq, const float* __restrict__ bq,
        const float* __restrict__ Wk, const float* __restrict__ bk,
        const float* __restrict__ Wv, const float* __restrict__ bv,
        float* __restrict__ q, float* __restrict__ k, float* __restrict__ v) {
    __shared__ float Ws[3 * D * D];    // 12 KB
    __shared__ float hs[8][D];
    for (int i = threadIdx.x; i < D * D; i += 256) {
        Ws[i] = Wq[i];
        Ws[D * D + i] = Wk[i];
        Ws[2 * D * D + i] = Wv[i];
    }
    int ln = threadIdx.x >> 5, col = threadIdx.x & 31;
    int node = blockIdx.x * 8 + ln;
    hs[ln][col] = h[(size_t)node * D + col];
    __syncthreads();
    float aq = bq[col], ak = bk[col], av = bv[col];
    #pragma unroll
    for (int i = 0; i < D; ++i) {
        float hv = hs[ln][i];
        aq = fmaf(hv, Ws[i * D + col], aq);
        ak = fmaf(hv, Ws[D * D + i * D + col], ak);
        av = fmaf(hv, Ws[2 * D * D + i * D + col], av);
    }
    size_t o = (size_t)node * D + col;
    q[o] = aq; k[o] = ak; v[o] = av;
}

__global__ void k_zero_i32(int* __restrict__ p, int n) {
    int i = blockIdx.x * blockDim.x + threadIdx.x;
    if (i < n) p[i] = 0;
}

__global__ void k_deg(const int* __restrict__ dst, int* __restrict__ deg) {
    int e = blockIdx.x * blockDim.x + threadIdx.x;
    if (e < NE) atomicAdd(&deg[dst[e]], 1);
}

// block-level exclusive scan (Hillis-Steele inclusive, then subtract self)
__global__ __launch_bounds__(1024) void k_scan1(const int* __restrict__ deg,
        int* __restrict__ rs, int* __restrict__ bsum) {
    __shared__ int s[1024];
    int i = blockIdx.x * 1024 + threadIdx.x;
    int v = (i < NN) ? deg[i] : 0;
    s[threadIdx.x] = v;
    __syncthreads();
    for (int off = 1; off < 1024; off <<= 1) {
        int t = (threadIdx.x >= off) ? s[threadIdx.x - off] : 0;
        __syncthreads();
        s[threadIdx.x] += t;
        __syncthreads();
    }
    if (i < NN) rs[i] = s[threadIdx.x] - v;
    if (threadIdx.x == 1023) bsum[blockIdx.x] = s[1023];
}

__global__ __launch_bounds__(128) void k_scan2(int* __restrict__ bsum, int nb) {
    __shared__ int s[128];
    int v = (threadIdx.x < nb) ? bsum[threadIdx.x] : 0;
    s[threadIdx.x] = v;
    __syncthreads();
    for (int off = 1; off < 128; off <<= 1) {
        int t = (threadIdx.x >= off) ? s[threadIdx.x - off] : 0;
        __syncthreads();
        s[threadIdx.x] += t;
        __syncthreads();
    }
    if (threadIdx.x < nb) bsum[threadIdx.x] = s[threadIdx.x] - v;  // exclusive
}

__global__ __launch_bounds__(1024) void k_scan3(int* __restrict__ rs,
        const int* __restrict__ bsum) {
    int i = blockIdx.x * 1024 + threadIdx.x;
    if (i < NN) rs[i] += bsum[blockIdx.x];
}

// ---- binned CSR build ----
// pass A: per-(block,bucket) histogram
__global__ __launch_bounds__(256) void k_binA(const int* __restrict__ dst,
        int* __restrict__ blockHist) {
    __shared__ int hist[NBKT];
    for (int i = threadIdx.x; i < NBKT; i += 256) hist[i] = 0;
    __syncthreads();
    int base = blockIdx.x * EPB;
    for (int i = threadIdx.x; i < EPB; i += 256)
        atomicAdd(&hist[dst[base + i] >> 10], 1);
    __syncthreads();
    for (int i = threadIdx.x; i < NBKT; i += 256)
        blockHist[i * NBLK + blockIdx.x] = hist[i];
}

// pass B: per-bucket exclusive scan over blocks, + bucket base from rs
__global__ __launch_bounds__(NBLK) void k_binB(int* __restrict__ blockHist,
        const int* __restrict__ rs) {
    __shared__ int s[NBLK];
    int b = blockIdx.x;
    int v = blockHist[b * NBLK + threadIdx.x];
    s[threadIdx.x] = v;
    __syncthreads();
    for (int off = 1; off < NBLK; off <<= 1) {
        int t = (threadIdx.x >= off) ? s[threadIdx.x - off] : 0;
        __syncthreads();
        s[threadIdx.x] += t;
        __syncthreads();
    }
    blockHist[b * NBLK + threadIdx.x] = rs[b << 10] + s[threadIdx.x] - v;
}

// pass C: place edges into bucket-ordered tmp; each block writes contiguous
// private chunks per bucket (single-CU temporal clustering => full-line combining)
__global__ __launch_bounds__(256) void k_binC(const int* __restrict__ src,
        const int* __restrict__ dst, const int* __restrict__ blockHist,
        unsigned int* __restrict__ tmp) {
    __shared__ int offs[NBKT];
    for (int i = threadIdx.x; i < NBKT; i += 256)
        offs[i] = blockHist[i * NBLK + blockIdx.x];
    __syncthreads();
    int base = blockIdx.x * EPB;
    for (int i = threadIdx.x; i < EPB; i += 256) {
        int d = dst[base + i];
        unsigned int sn = (unsigned int)src[base + i];
        int pos = atomicAdd(&offs[d >> 10], 1);
        tmp[pos] = sn | ((unsigned int)(d & 1023) << 17);
    }
}

// pass D: within-bucket exact placement; writes confined to <=128KB L2 window
__global__ __launch_bounds__(256) void k_binD(const unsigned int* __restrict__ tmp,
        const int* __restrict__ rs, int* __restrict__ cnt, int* __restrict__ csr) {
    int b = blockIdx.x / DSPLIT;
    int j = blockIdx.x % DSPLIT;
    int startN = b << 10;
    int s0 = rs[startN];
    int s1 = (b == NBKT - 1) ? NE : rs[(b + 1) << 10];
    int len = s1 - s0;
    int q0 = s0 + (int)(((long long)len * j) / DSPLIT);
    int q1 = s0 + (int)(((long long)len * (j + 1)) / DSPLIT);
    for (int i = q0 + threadIdx.x; i < q1; i += 256) {
        unsigned int p = tmp[i];
        int sn = (int)(p & 0x1FFFFu);
        int d = startN + (int)(p >> 17);
        int pos = atomicAdd(&cnt[d], 1);
        csr[rs[d] + pos] = sn;
    }
}

// fused per-dst attention: one wave per node; lanes = 16 edge-slots x 4 heads
__global__ __launch_bounds__(256) void k_attn(const float* __restrict__ q,
        const float* __restrict__ kk, const float* __restrict__ vv,
        const int* __restrict__ rs, const int* __restrict__ deg,
        const int* __restrict__ csr_src, float* __restrict__ attn) {
    int wid = (blockIdx.x * 256 + threadIdx.x) >> 6;
    int lane = threadIdx.x & 63;
    if (wid >= NN) return;
    int eslot = lane >> 2, head = lane & 3;
    int start = rs[wid], g = deg[wid];
    const float4* kr = (const float4*)(kk + (size_t)wid * D + head * HD);
    float4 k0 = kr[0], k1 = kr[1];
    float m = -INFINITY, l = 0.f;
    float acc[HD];
    #pragma unroll
    for (int i = 0; i < HD; ++i) acc[i] = 0.f;
    for (int base = 0; base < g; base += 16) {
        int idx = base + eslot;
        bool act = idx < g;
        int sn = act ? csr_src[start + idx] : 0;
        float s = -INFINITY;
        if (act) {
            const float4* qr = (const float4*)(q + (size_t)sn * D + head * HD);
            float4 q0 = qr[0], q1 = qr[1];
            s = (q0.x * k0.x + q0.y * k0.y + q0.z * k0.z + q0.w * k0.w
               + q1.x * k1.x + q1.y * k1.y + q1.z * k1.z + q1.w * k1.w)
              * 0.35355339059327376f;
        }
        float cm = s;
        #pragma unroll
        for (int off = 4; off < 64; off <<= 1)
            cm = fmaxf(cm, __shfl_xor(cm, off));
        float nm = fmaxf(m, cm);
        float scale = __expf(m - nm);
        m = nm;
        l *= scale;
        #pragma unroll
        for (int i = 0; i < HD; ++i) acc[i] *= scale;
        if (act) {
            float p = __expf(s - nm);
            l += p;
            const float4* vr = (const float4*)(vv + (size_t)sn * D + head * HD);
            float4 v0 = vr[0], v1 = vr[1];
            acc[0] = fmaf(p, v0.x, acc[0]); acc[1] = fmaf(p, v0.y, acc[1]);
            acc[2] = fmaf(p, v0.z, acc[2]); acc[3] = fmaf(p, v0.w, acc[3]);
            acc[4] = fmaf(p, v1.x, acc[4]); acc[5] = fmaf(p, v1.y, acc[5]);
            acc[6] = fmaf(p, v1.z, acc[6]); acc[7] = fmaf(p, v1.w, acc[7]);
        }
    }
    #pragma unroll
    for (int off = 4; off < 64; off <<= 1) {
        l += __shfl_xor(l, off);
        #pragma unroll
        for (int i = 0; i < HD; ++i) acc[i] += __shfl_xor(acc[i], off);
    }
    if (eslot == 0) {
        float inv = (l > 0.f) ? 1.0f / l : 0.f;
        float* outp = attn + (size_t)wid * D + head * HD;
        #pragma unroll
        for (int i = 0; i < HD; ++i) outp[i] = acc[i] * inv;
    }
}

// h += attn @ Wo + bo
__global__ __launch_bounds__(256) void k_oproj(const float* __restrict__ attn,
        const float* __restrict__ Wo, const float* __restrict__ bo,
        float* __restrict__ h) {
    __shared__ float Ws[D * D];
    __shared__ float as[8][D];
    for (int i = threadIdx.x; i < D * D; i += 256) Ws[i] = Wo[i];
    int ln = threadIdx.x >> 5, col = threadIdx.x & 31;
    int node = blockIdx.x * 8 + ln;
    as[ln][col] = attn[(size_t)node * D + col];
    __syncthreads();
    float a = bo[col];
    #pragma unroll
    for (int i = 0; i < D; ++i) a = fmaf(as[ln][i], Ws[i * D + col], a);
    h[(size_t)node * D + col] += a;
}

// h += gelu(h @ W1 + b1) @ W2 + b2
__global__ __launch_bounds__(256) void k_ffn(const float* __restrict__ W1,
        const float* __restrict__ b1, const float* __restrict__ W2,
        const float* __restrict__ b2, float* __restrict__ h) {
    __shared__ float Ws1[D * D], Ws2[D * D];
    __shared__ float hs[8][D], ts[8][D];
    for (int i = threadIdx.x; i < D * D; i += 256) { Ws1[i] = W1[i]; Ws2[i] = W2[i]; }
    int ln = threadIdx.x >> 5, col = threadIdx.x & 31;
    int node = blockIdx.x * 8 + ln;
    float hval = h[(size_t)node * D + col];
    hs[ln][col] = hval;
    __syncthreads();
    float t = b1[col];
    #pragma unroll
    for (int i = 0; i < D; ++i) t = fmaf(hs[ln][i], Ws1[i * D + col], t);
    ts[ln][col] = gelu_f(t);
    __syncthreads();
    float o = b2[col];
    #pragma unroll
    for (int i = 0; i < D; ++i) o = fmaf(ts[ln][i], Ws2[i * D + col], o);
    h[(size_t)node * D + col] = hval + o;
}

// out = h @ W_out + b_out
__global__ void k_out(const float* __restrict__ h, const float* __restrict__ W,
        const float* __restrict__ b, float* __restrict__ out) {
    int n = blockIdx.x * blockDim.x + threadIdx.x;
    if (n >= NN) return;
    const float4* hr = (const float4*)(h + (size_t)n * D);
    float a0 = b[0], a1 = b[1];
    #pragma unroll
    for (int i = 0; i < 8; ++i) {
        float4 hv = hr[i];
        a0 += hv.x * W[(i * 4 + 0) * 2 + 0] + hv.y * W[(i * 4 + 1) * 2 + 0]
            + hv.z * W[(i * 4 + 2) * 2 + 0] + hv.w * W[(i * 4 + 3) * 2 + 0];
        a1 += hv.x * W[(i * 4 + 0) * 2 + 1] + hv.y * W[(i * 4 + 1) * 2 + 1]
            + hv.z * W[(i * 4 + 2) * 2 + 1] + hv.w * W[(i * 4 + 3) * 2 + 1];
    }
    out[n * 2 + 0] = a0;
    out[n * 2 + 1] = a1;
}

extern "C" void kernel_launch(void* const* d_in, const int* in_sizes, int n_in,
                              void* d_out, int out_size, void* d_ws, size_t ws_size,
                              hipStream_t stream) {
    const float* x     = (const float*)d_in[0];
    const int*   src   = (const int*)d_in[1];
    const int*   dst   = (const int*)d_in[2];
    const float* W_in  = (const float*)d_in[3];
    const float* b_in  = (const float*)d_in[4];
    const float* Wq    = (const float*)d_in[5];
    const float* bq    = (const float*)d_in[6];
    const float* Wk    = (const float*)d_in[7];
    const float* bk    = (const float*)d_in[8];
    const float* Wv    = (const float*)d_in[9];
    const float* bv    = (const float*)d_in[10];
    const float* Wo    = (const float*)d_in[11];
    const float* bo    = (const float*)d_in[12];
    const float* W1    = (const float*)d_in[13];
    const float* b1    = (const float*)d_in[14];
    const float* W2    = (const float*)d_in[15];
    const float* b2    = (const float*)d_in[16];
    const float* W_out = (const float*)d_in[17];
    const float* b_out = (const float*)d_in[18];
    float* out = (float*)d_out;

    char* w = (char*)d_ws;
    size_t off = 0;
    auto alloc = [&](size_t bytes) -> void* {
        void* p = w + off;
        off += (bytes + 255) & ~(size_t)255;
        return p;
    };
    float* h    = (float*)alloc((size_t)NN * D * 4);
    float* q    = (float*)alloc((size_t)NN * D * 4);
    float* kk   = (float*)alloc((size_t)NN * D * 4);
    float* vv   = (float*)alloc((size_t)NN * D * 4);
    float* attn = (float*)alloc((size_t)NN * D * 4);   // aliased as tmp during CSR build
    int* deg    = (int*)alloc((size_t)NN * 4);
    int* rs     = (int*)alloc((size_t)NN * 4);
    int* cnt    = (int*)alloc((size_t)NN * 4);
    int* bsum   = (int*)alloc(1024);
    int* bhist  = (int*)alloc((size_t)NBKT * NBLK * 4);
    int* csr    = (int*)alloc((size_t)NE * 4);
    unsigned int* tmp = (unsigned int*)attn;           // NE*4 == NN*D*4 bytes
    (void)ws_size; (void)in_sizes; (void)n_in; (void)out_size;

    const int NB_SCAN = (NN + 1023) / 1024;  // 98

    k_in_proj<<<NN / 8, 256, 0, stream>>>(x, W_in, b_in, h);
    k_zero_i32<<<(NN + 255) / 256, 256, 0, stream>>>(deg, NN);
    k_zero_i32<<<(NN + 255) / 256, 256, 0, stream>>>(cnt, NN);
    k_deg<<<NE / 256, 256, 0, stream>>>(dst, deg);
    k_scan1<<<NB_SCAN, 1024, 0, stream>>>(deg, rs, bsum);
    k_scan2<<<1, 128, 0, stream>>>(bsum, NB_SCAN);
    k_scan3<<<NB_SCAN, 1024, 0, stream>>>(rs, bsum);
    k_binA<<<NBLK, 256, 0, stream>>>(dst, bhist);
    k_binB<<<NBKT, NBLK, 0, stream>>>(bhist, rs);
    k_binC<<<NBLK, 256, 0, stream>>>(src, dst, bhist, tmp);
    k_binD<<<NBKT * DSPLIT, 256, 0, stream>>>(tmp, rs, cnt, csr);

    for (int l = 0; l < 2; ++l) {
        k_qkv<<<NN / 8, 256, 0, stream>>>(h, Wq + l * D * D, bq + l * D,
                                          Wk + l * D * D, bk + l * D,
                                          Wv + l * D * D, bv + l * D, q, kk, vv);
        k_attn<<<NN / 4, 256, 0, stream>>>(q, kk, vv, rs, deg, csr, attn);
        k_oproj<<<NN / 8, 256, 0, stream>>>(attn, Wo + l * D * D, bo + l * D, h);
        k_ffn<<<NN / 8, 256, 0, stream>>>(W1 + l * D * D, b1 + l * D,
                                          W2 + l * D * D, b2 + l * D, h);
    }
    k_out<<<(NN + 255) / 256, 256, 0, stream>>>(h, W_out, b_out, out);
}

// Round 3
// 480.520 us; speedup vs baseline: 1.5971x; 1.5971x over previous
//
#include <hip/hip_runtime.h>
#include <math.h>

#define NN 100000
#define NE 3200000
#define INF_ 128
#define D 32
#define H 4
#define HD 8

// binning config: bucket = dst >> 8 (256 dst nodes per bucket)
#define BSH 8
#define BNODES 256
#define NBKT 391                // ceil(100000/256)
#define NBLK 128                // chunking blocks for passes A/C
#define EPB (NE / NBLK)         // 25000 edges per block
#define CAP 12288               // LDS sorted capacity (mean 8192, 45 sigma headroom)

__device__ __forceinline__ float gelu_f(float x) {
    return 0.5f * x * (1.0f + erff(x * 0.70710678118654752f));
}

// h = gelu(x @ W_in + b_in); block = 256 threads = 8 nodes x 32 cols
__global__ __launch_bounds__(256) void k_in_proj(const float* __restrict__ x,
        const float* __restrict__ W, const float* __restrict__ b,
        float* __restrict__ h) {
    __shared__ float Ws[INF_ * D];     // 16 KB
    __shared__ float xs[8][INF_];      // 4 KB
    for (int i = threadIdx.x; i < INF_ * D; i += 256) Ws[i] = W[i];
    int ln = threadIdx.x >> 5;
    int col = threadIdx.x & 31;
    int node = blockIdx.x * 8 + ln;    // NN/8 = 12500 exact
    const float4* xr = (const float4*)(x + (size_t)node * INF_);
    ((float4*)xs[ln])[col] = xr[col];
    __syncthreads();
    float acc = b[col];
    #pragma unroll 16
    for (int i = 0; i < INF_; ++i) acc = fmaf(xs[ln][i], Ws[i * D + col], acc);
    h[(size_t)node * D + col] = gelu_f(acc);
}

// q,k,v = h @ {Wq,Wk,Wv} + bias; 8 nodes per block
__global__ __launch_bounds__(256) void k_qkv(const float* __restrict__ h,
        const float* __restrict__ Wq, const float* __restrict__ bq,
        const float* __restrict__ Wk, const float* __restrict__ bk,
        const float* __restrict__ Wv, const float* __restrict__ bv,
        float* __restrict__ q, float* __restrict__ k, float* __restrict__ v) {
    __shared__ float Ws[3 * D * D];    // 12 KB
    __shared__ float hs[8][D];
    for (int i = threadIdx.x; i < D * D; i += 256) {
        Ws[i] = Wq[i];
        Ws[D * D + i] = Wk[i];
        Ws[2 * D * D + i] = Wv[i];
    }
    int ln = threadIdx.x >> 5, col = threadIdx.x & 31;
    int node = blockIdx.x * 8 + ln;
    hs[ln][col] = h[(size_t)node * D + col];
    __syncthreads();
    float aq = bq[col], ak = bk[col], av = bv[col];
    #pragma unroll
    for (int i = 0; i < D; ++i) {
        float hv = hs[ln][i];
        aq = fmaf(hv, Ws[i * D + col], aq);
        ak = fmaf(hv, Ws[D * D + i * D + col], ak);
        av = fmaf(hv, Ws[2 * D * D + i * D + col], av);
    }
    size_t o = (size_t)node * D + col;
    q[o] = aq; k[o] = ak; v[o] = av;
}

// ---- binned CSR build ----
// pass A: per-(block,bucket) histogram
__global__ __launch_bounds__(256) void k_binA(const int* __restrict__ dst,
        int* __restrict__ bhist) {
    __shared__ int hist[NBKT];
    for (int i = threadIdx.x; i < NBKT; i += 256) hist[i] = 0;
    __syncthreads();
    int base = blockIdx.x * EPB;
    for (int i = threadIdx.x; i < EPB; i += 256)
        atomicAdd(&hist[dst[base + i] >> BSH], 1);
    __syncthreads();
    for (int i = threadIdx.x; i < NBKT; i += 256)
        bhist[i * NBLK + blockIdx.x] = hist[i];
}

// pass B1: per-bucket exclusive scan over blocks (in place), total -> btot
__global__ __launch_bounds__(NBLK) void k_binB1(int* __restrict__ bhist,
        int* __restrict__ btot) {
    __shared__ int s[NBLK];
    int b = blockIdx.x;
    int v = bhist[b * NBLK + threadIdx.x];
    s[threadIdx.x] = v;
    __syncthreads();
    for (int off = 1; off < NBLK; off <<= 1) {
        int t = (threadIdx.x >= off) ? s[threadIdx.x - off] : 0;
        __syncthreads();
        s[threadIdx.x] += t;
        __syncthreads();
    }
    bhist[b * NBLK + threadIdx.x] = s[threadIdx.x] - v;   // exclusive within bucket
    if (threadIdx.x == NBLK - 1) btot[b] = s[NBLK - 1];
}

// pass B2: exclusive scan of bucket totals -> bbase[NBKT+1]
__global__ __launch_bounds__(512) void k_binB2(const int* __restrict__ btot,
        int* __restrict__ bbase) {
    __shared__ int s[512];
    int v = (threadIdx.x < NBKT) ? btot[threadIdx.x] : 0;
    s[threadIdx.x] = v;
    __syncthreads();
    for (int off = 1; off < 512; off <<= 1) {
        int t = (threadIdx.x >= off) ? s[threadIdx.x - off] : 0;
        __syncthreads();
        s[threadIdx.x] += t;
        __syncthreads();
    }
    if (threadIdx.x < NBKT) bbase[threadIdx.x] = s[threadIdx.x] - v;
    if (threadIdx.x == NBKT - 1) bbase[NBKT] = s[threadIdx.x];  // == NE
}

// pass C: place edges into bucket-ordered tmp; each block writes contiguous
// private chunks per bucket. payload = src (17b) | local_dst (8b) << 17
__global__ __launch_bounds__(256) void k_binC(const int* __restrict__ src,
        const int* __restrict__ dst, const int* __restrict__ bhist,
        const int* __restrict__ bbase, unsigned int* __restrict__ tmp) {
    __shared__ int offs[NBKT];
    for (int i = threadIdx.x; i < NBKT; i += 256)
        offs[i] = bhist[i * NBLK + blockIdx.x] + bbase[i];
    __syncthreads();
    int base = blockIdx.x * EPB;
    for (int i = threadIdx.x; i < EPB; i += 256) {
        int d = dst[base + i];
        unsigned int sn = (unsigned int)src[base + i];
        int pos = atomicAdd(&offs[d >> BSH], 1);
        tmp[pos] = sn | ((unsigned int)(d & (BNODES - 1)) << 17);
    }
}

// pass D: per-bucket LDS counting sort; streams full cache lines to csr.
// Also emits rs[node] and deg[node] (replaces global deg/scan kernels).
__global__ __launch_bounds__(256) void k_binD(const unsigned int* __restrict__ tmp,
        const int* __restrict__ bbase, int* __restrict__ csr,
        int* __restrict__ rs, int* __restrict__ deg) {
    __shared__ int lcnt[BNODES];
    __shared__ int lscan[BNODES];
    __shared__ int sorted[CAP];
    int b = blockIdx.x;
    int s0 = bbase[b], s1 = bbase[b + 1];
    int len = s1 - s0;
    lcnt[threadIdx.x] = 0;
    __syncthreads();
    for (int i = s0 + threadIdx.x; i < s1; i += 256)
        atomicAdd(&lcnt[tmp[i] >> 17], 1);
    __syncthreads();
    int v = lcnt[threadIdx.x];
    lscan[threadIdx.x] = v;
    __syncthreads();
    for (int off = 1; off < BNODES; off <<= 1) {
        int t = (threadIdx.x >= off) ? lscan[threadIdx.x - off] : 0;
        __syncthreads();
        lscan[threadIdx.x] += t;
        __syncthreads();
    }
    int excl = lscan[threadIdx.x] - v;
    int node = (b << BSH) + threadIdx.x;
    if (node < NN) {
        rs[node] = s0 + excl;
        deg[node] = v;
    }
    lcnt[threadIdx.x] = excl;   // reuse as placement cursor
    __syncthreads();
    if (len <= CAP) {
        for (int i = s0 + threadIdx.x; i < s1; i += 256) {
            unsigned int p = tmp[i];
            int pos = atomicAdd(&lcnt[p >> 17], 1);
            sorted[pos] = (int)(p & 0x1FFFFu);
        }
        __syncthreads();
        for (int j = threadIdx.x; j < len; j += 256)
            csr[s0 + j] = sorted[j];
    } else {  // overflow fallback (never for this input): direct placement
        for (int i = s0 + threadIdx.x; i < s1; i += 256) {
            unsigned int p = tmp[i];
            int pos = atomicAdd(&lcnt[p >> 17], 1);
            csr[s0 + pos] = (int)(p & 0x1FFFFu);
        }
    }
}

// fused per-dst attention: one wave per node; lanes = 16 edge-slots x 4 heads
__global__ __launch_bounds__(256) void k_attn(const float* __restrict__ q,
        const float* __restrict__ kk, const float* __restrict__ vv,
        const int* __restrict__ rs, const int* __restrict__ deg,
        const int* __restrict__ csr_src, float* __restrict__ attn) {
    int wid = (blockIdx.x * 256 + threadIdx.x) >> 6;
    int lane = threadIdx.x & 63;
    if (wid >= NN) return;
    int eslot = lane >> 2, head = lane & 3;
    int start = rs[wid], g = deg[wid];
    const float4* kr = (const float4*)(kk + (size_t)wid * D + head * HD);
    float4 k0 = kr[0], k1 = kr[1];
    float m = -INFINITY, l = 0.f;
    float acc[HD];
    #pragma unroll
    for (int i = 0; i < HD; ++i) acc[i] = 0.f;
    for (int base = 0; base < g; base += 16) {
        int idx = base + eslot;
        bool act = idx < g;
        int sn = act ? csr_src[start + idx] : 0;
        float s = -INFINITY;
        if (act) {
            const float4* qr = (const float4*)(q + (size_t)sn * D + head * HD);
            float4 q0 = qr[0], q1 = qr[1];
            s = (q0.x * k0.x + q0.y * k0.y + q0.z * k0.z + q0.w * k0.w
               + q1.x * k1.x + q1.y * k1.y + q1.z * k1.z + q1.w * k1.w)
              * 0.35355339059327376f;
        }
        float cm = s;
        #pragma unroll
        for (int off = 4; off < 64; off <<= 1)
            cm = fmaxf(cm, __shfl_xor(cm, off));
        float nm = fmaxf(m, cm);
        float scale = __expf(m - nm);
        m = nm;
        l *= scale;
        #pragma unroll
        for (int i = 0; i < HD; ++i) acc[i] *= scale;
        if (act) {
            float p = __expf(s - nm);
            l += p;
            const float4* vr = (const float4*)(vv + (size_t)sn * D + head * HD);
            float4 v0 = vr[0], v1 = vr[1];
            acc[0] = fmaf(p, v0.x, acc[0]); acc[1] = fmaf(p, v0.y, acc[1]);
            acc[2] = fmaf(p, v0.z, acc[2]); acc[3] = fmaf(p, v0.w, acc[3]);
            acc[4] = fmaf(p, v1.x, acc[4]); acc[5] = fmaf(p, v1.y, acc[5]);
            acc[6] = fmaf(p, v1.z, acc[6]); acc[7] = fmaf(p, v1.w, acc[7]);
        }
    }
    #pragma unroll
    for (int off = 4; off < 64; off <<= 1) {
        l += __shfl_xor(l, off);
        #pragma unroll
        for (int i = 0; i < HD; ++i) acc[i] += __shfl_xor(acc[i], off);
    }
    if (eslot == 0) {
        float inv = (l > 0.f) ? 1.0f / l : 0.f;
        float* outp = attn + (size_t)wid * D + head * HD;
        #pragma unroll
        for (int i = 0; i < HD; ++i) outp[i] = acc[i] * inv;
    }
}

// h += attn @ Wo + bo
__global__ __launch_bounds__(256) void k_oproj(const float* __restrict__ attn,
        const float* __restrict__ Wo, const float* __restrict__ bo,
        float* __restrict__ h) {
    __shared__ float Ws[D * D];
    __shared__ float as[8][D];
    for (int i = threadIdx.x; i < D * D; i += 256) Ws[i] = Wo[i];
    int ln = threadIdx.x >> 5, col = threadIdx.x & 31;
    int node = blockIdx.x * 8 + ln;
    as[ln][col] = attn[(size_t)node * D + col];
    __syncthreads();
    float a = bo[col];
    #pragma unroll
    for (int i = 0; i < D; ++i) a = fmaf(as[ln][i], Ws[i * D + col], a);
    h[(size_t)node * D + col] += a;
}

// h += gelu(h @ W1 + b1) @ W2 + b2
__global__ __launch_bounds__(256) void k_ffn(const float* __restrict__ W1,
        const float* __restrict__ b1, const float* __restrict__ W2,
        const float* __restrict__ b2, float* __restrict__ h) {
    __shared__ float Ws1[D * D], Ws2[D * D];
    __shared__ float hs[8][D], ts[8][D];
    for (int i = threadIdx.x; i < D * D; i += 256) { Ws1[i] = W1[i]; Ws2[i] = W2[i]; }
    int ln = threadIdx.x >> 5, col = threadIdx.x & 31;
    int node = blockIdx.x * 8 + ln;
    float hval = h[(size_t)node * D + col];
    hs[ln][col] = hval;
    __syncthreads();
    float t = b1[col];
    #pragma unroll
    for (int i = 0; i < D; ++i) t = fmaf(hs[ln][i], Ws1[i * D + col], t);
    ts[ln][col] = gelu_f(t);
    __syncthreads();
    float o = b2[col];
    #pragma unroll
    for (int i = 0; i < D; ++i) o = fmaf(ts[ln][i], Ws2[i * D + col], o);
    h[(size_t)node * D + col] = hval + o;
}

// out = h @ W_out + b_out
__global__ void k_out(const float* __restrict__ h, const float* __restrict__ W,
        const float* __restrict__ b, float* __restrict__ out) {
    int n = blockIdx.x * blockDim.x + threadIdx.x;
    if (n >= NN) return;
    const float4* hr = (const float4*)(h + (size_t)n * D);
    float a0 = b[0], a1 = b[1];
    #pragma unroll
    for (int i = 0; i < 8; ++i) {
        float4 hv = hr[i];
        a0 += hv.x * W[(i * 4 + 0) * 2 + 0] + hv.y * W[(i * 4 + 1) * 2 + 0]
            + hv.z * W[(i * 4 + 2) * 2 + 0] + hv.w * W[(i * 4 + 3) * 2 + 0];
        a1 += hv.x * W[(i * 4 + 0) * 2 + 1] + hv.y * W[(i * 4 + 1) * 2 + 1]
            + hv.z * W[(i * 4 + 2) * 2 + 1] + hv.w * W[(i * 4 + 3) * 2 + 1];
    }
    out[n * 2 + 0] = a0;
    out[n * 2 + 1] = a1;
}

extern "C" void kernel_launch(void* const* d_in, const int* in_sizes, int n_in,
                              void* d_out, int out_size, void* d_ws, size_t ws_size,
                              hipStream_t stream) {
    const float* x     = (const float*)d_in[0];
    const int*   src   = (const int*)d_in[1];
    const int*   dst   = (const int*)d_in[2];
    const float* W_in  = (const float*)d_in[3];
    const float* b_in  = (const float*)d_in[4];
    const float* Wq    = (const float*)d_in[5];
    const float* bq    = (const float*)d_in[6];
    const float* Wk    = (const float*)d_in[7];
    const float* bk    = (const float*)d_in[8];
    const float* Wv    = (const float*)d_in[9];
    const float* bv    = (const float*)d_in[10];
    const float* Wo    = (const float*)d_in[11];
    const float* bo    = (const float*)d_in[12];
    const float* W1    = (const float*)d_in[13];
    const float* b1    = (const float*)d_in[14];
    const float* W2    = (const float*)d_in[15];
    const float* b2    = (const float*)d_in[16];
    const float* W_out = (const float*)d_in[17];
    const float* b_out = (const float*)d_in[18];
    float* out = (float*)d_out;

    char* w = (char*)d_ws;
    size_t off = 0;
    auto alloc = [&](size_t bytes) -> void* {
        void* p = w + off;
        off += (bytes + 255) & ~(size_t)255;
        return p;
    };
    float* h    = (float*)alloc((size_t)NN * D * 4);
    float* q    = (float*)alloc((size_t)NN * D * 4);
    float* kk   = (float*)alloc((size_t)NN * D * 4);
    float* vv   = (float*)alloc((size_t)NN * D * 4);
    float* attn = (float*)alloc((size_t)NN * D * 4);   // aliased as tmp during CSR build
    int* deg    = (int*)alloc((size_t)NN * 4);
    int* rs     = (int*)alloc((size_t)NN * 4);
    int* bhist  = (int*)alloc((size_t)NBKT * NBLK * 4);
    int* btot   = (int*)alloc((size_t)NBKT * 4);
    int* bbase  = (int*)alloc((size_t)(NBKT + 1) * 4);
    int* csr    = (int*)alloc((size_t)NE * 4);
    unsigned int* tmp = (unsigned int*)attn;           // NE*4 == NN*D*4 bytes
    (void)ws_size; (void)in_sizes; (void)n_in; (void)out_size;

    k_in_proj<<<NN / 8, 256, 0, stream>>>(x, W_in, b_in, h);
    k_binA<<<NBLK, 256, 0, stream>>>(dst, bhist);
    k_binB1<<<NBKT, NBLK, 0, stream>>>(bhist, btot);
    k_binB2<<<1, 512, 0, stream>>>(btot, bbase);
    k_binC<<<NBLK, 256, 0, stream>>>(src, dst, bhist, bbase, tmp);
    k_binD<<<NBKT, 256, 0, stream>>>(tmp, bbase, csr, rs, deg);

    for (int l = 0; l < 2; ++l) {
        k_qkv<<<NN / 8, 256, 0, stream>>>(h, Wq + l * D * D, bq + l * D,
                                          Wk + l * D * D, bk + l * D,
                                          Wv + l * D * D, bv + l * D, q, kk, vv);
        k_attn<<<NN / 4, 256, 0, stream>>>(q, kk, vv, rs, deg, csr, attn);
        k_oproj<<<NN / 8, 256, 0, stream>>>(attn, Wo + l * D * D, bo + l * D, h);
        k_ffn<<<NN / 8, 256, 0, stream>>>(W1 + l * D * D, b1 + l * D,
                                          W2 + l * D * D, b2 + l * D, h);
    }
    k_out<<<(NN + 255) / 256, 256, 0, stream>>>(h, W_out, b_out, out);
}

// Round 4
// 445.131 us; speedup vs baseline: 1.7241x; 1.0795x over previous
//
#include <hip/hip_runtime.h>
#include <hip/hip_fp16.h>
#include <math.h>

#define NN 100000
#define NE 3200000
#define INF_ 128
#define D 32
#define H 4
#define HD 8

// binning config: bucket = dst >> 8 (256 dst nodes per bucket)
#define BSH 8
#define BNODES 256
#define NBKT 391                // ceil(100000/256)
#define NBLK 128                // chunking blocks for passes A/C
#define EPB (NE / NBLK)         // 25000 edges per block
#define CAP 12288               // LDS sorted capacity

__device__ __forceinline__ float gelu_f(float x) {
    return 0.5f * x * (1.0f + erff(x * 0.70710678118654752f));
}

// h = gelu(x @ W_in + b_in); block = 256 threads = 8 nodes x 32 cols
__global__ __launch_bounds__(256) void k_in_proj(const float* __restrict__ x,
        const float* __restrict__ W, const float* __restrict__ b,
        float* __restrict__ h) {
    __shared__ float Ws[INF_ * D];     // 16 KB
    __shared__ float xs[8][INF_];      // 4 KB
    for (int i = threadIdx.x; i < INF_ * D; i += 256) Ws[i] = W[i];
    int ln = threadIdx.x >> 5;
    int col = threadIdx.x & 31;
    int node = blockIdx.x * 8 + ln;    // NN/8 = 12500 exact
    const float4* xr = (const float4*)(x + (size_t)node * INF_);
    ((float4*)xs[ln])[col] = xr[col];
    __syncthreads();
    float acc = b[col];
    #pragma unroll 16
    for (int i = 0; i < INF_; ++i) acc = fmaf(xs[ln][i], Ws[i * D + col], acc);
    h[(size_t)node * D + col] = gelu_f(acc);
}

// q,k,v = h @ {Wq,Wk,Wv} + bias; 8 nodes per block; fp16 outputs
__global__ __launch_bounds__(256) void k_qkv(const float* __restrict__ h,
        const float* __restrict__ Wq, const float* __restrict__ bq,
        const float* __restrict__ Wk, const float* __restrict__ bk,
        const float* __restrict__ Wv, const float* __restrict__ bv,
        __half* __restrict__ q, __half* __restrict__ k, __half* __restrict__ v) {
    __shared__ float Ws[3 * D * D];    // 12 KB
    __shared__ float hs[8][D];
    for (int i = threadIdx.x; i < D * D; i += 256) {
        Ws[i] = Wq[i];
        Ws[D * D + i] = Wk[i];
        Ws[2 * D * D + i] = Wv[i];
    }
    int ln = threadIdx.x >> 5, col = threadIdx.x & 31;
    int node = blockIdx.x * 8 + ln;
    hs[ln][col] = h[(size_t)node * D + col];
    __syncthreads();
    float aq = bq[col], ak = bk[col], av = bv[col];
    #pragma unroll
    for (int i = 0; i < D; ++i) {
        float hv = hs[ln][i];
        aq = fmaf(hv, Ws[i * D + col], aq);
        ak = fmaf(hv, Ws[D * D + i * D + col], ak);
        av = fmaf(hv, Ws[2 * D * D + i * D + col], av);
    }
    size_t o = (size_t)node * D + col;
    q[o] = __float2half(aq); k[o] = __float2half(ak); v[o] = __float2half(av);
}

// ---- binned CSR build ----
__global__ __launch_bounds__(256) void k_binA(const int* __restrict__ dst,
        int* __restrict__ bhist) {
    __shared__ int hist[NBKT];
    for (int i = threadIdx.x; i < NBKT; i += 256) hist[i] = 0;
    __syncthreads();
    int base = blockIdx.x * EPB;
    for (int i = threadIdx.x; i < EPB; i += 256)
        atomicAdd(&hist[dst[base + i] >> BSH], 1);
    __syncthreads();
    for (int i = threadIdx.x; i < NBKT; i += 256)
        bhist[i * NBLK + blockIdx.x] = hist[i];
}

__global__ __launch_bounds__(NBLK) void k_binB1(int* __restrict__ bhist,
        int* __restrict__ btot) {
    __shared__ int s[NBLK];
    int b = blockIdx.x;
    int v = bhist[b * NBLK + threadIdx.x];
    s[threadIdx.x] = v;
    __syncthreads();
    for (int off = 1; off < NBLK; off <<= 1) {
        int t = (threadIdx.x >= off) ? s[threadIdx.x - off] : 0;
        __syncthreads();
        s[threadIdx.x] += t;
        __syncthreads();
    }
    bhist[b * NBLK + threadIdx.x] = s[threadIdx.x] - v;
    if (threadIdx.x == NBLK - 1) btot[b] = s[NBLK - 1];
}

__global__ __launch_bounds__(512) void k_binB2(const int* __restrict__ btot,
        int* __restrict__ bbase) {
    __shared__ int s[512];
    int v = (threadIdx.x < NBKT) ? btot[threadIdx.x] : 0;
    s[threadIdx.x] = v;
    __syncthreads();
    for (int off = 1; off < 512; off <<= 1) {
        int t = (threadIdx.x >= off) ? s[threadIdx.x - off] : 0;
        __syncthreads();
        s[threadIdx.x] += t;
        __syncthreads();
    }
    if (threadIdx.x < NBKT) bbase[threadIdx.x] = s[threadIdx.x] - v;
    if (threadIdx.x == NBKT - 1) bbase[NBKT] = s[threadIdx.x];
}

__global__ __launch_bounds__(256) void k_binC(const int* __restrict__ src,
        const int* __restrict__ dst, const int* __restrict__ bhist,
        const int* __restrict__ bbase, unsigned int* __restrict__ tmp) {
    __shared__ int offs[NBKT];
    for (int i = threadIdx.x; i < NBKT; i += 256)
        offs[i] = bhist[i * NBLK + blockIdx.x] + bbase[i];
    __syncthreads();
    int base = blockIdx.x * EPB;
    for (int i = threadIdx.x; i < EPB; i += 256) {
        int d = dst[base + i];
        unsigned int sn = (unsigned int)src[base + i];
        int pos = atomicAdd(&offs[d >> BSH], 1);
        tmp[pos] = sn | ((unsigned int)(d & (BNODES - 1)) << 17);
    }
}

__global__ __launch_bounds__(256) void k_binD(const unsigned int* __restrict__ tmp,
        const int* __restrict__ bbase, int* __restrict__ csr,
        int* __restrict__ rs, int* __restrict__ deg) {
    __shared__ int lcnt[BNODES];
    __shared__ int lscan[BNODES];
    __shared__ int sorted[CAP];
    int b = blockIdx.x;
    int s0 = bbase[b], s1 = bbase[b + 1];
    int len = s1 - s0;
    lcnt[threadIdx.x] = 0;
    __syncthreads();
    for (int i = s0 + threadIdx.x; i < s1; i += 256)
        atomicAdd(&lcnt[tmp[i] >> 17], 1);
    __syncthreads();
    int v = lcnt[threadIdx.x];
    lscan[threadIdx.x] = v;
    __syncthreads();
    for (int off = 1; off < BNODES; off <<= 1) {
        int t = (threadIdx.x >= off) ? lscan[threadIdx.x - off] : 0;
        __syncthreads();
        lscan[threadIdx.x] += t;
        __syncthreads();
    }
    int excl = lscan[threadIdx.x] - v;
    int node = (b << BSH) + threadIdx.x;
    if (node < NN) {
        rs[node] = s0 + excl;
        deg[node] = v;
    }
    lcnt[threadIdx.x] = excl;
    __syncthreads();
    if (len <= CAP) {
        for (int i = s0 + threadIdx.x; i < s1; i += 256) {
            unsigned int p = tmp[i];
            int pos = atomicAdd(&lcnt[p >> 17], 1);
            sorted[pos] = (int)(p & 0x1FFFFu);
        }
        __syncthreads();
        for (int j = threadIdx.x; j < len; j += 256)
            csr[s0 + j] = sorted[j];
    } else {
        for (int i = s0 + threadIdx.x; i < s1; i += 256) {
            unsigned int p = tmp[i];
            int pos = atomicAdd(&lcnt[p >> 17], 1);
            csr[s0 + pos] = (int)(p & 0x1FFFFu);
        }
    }
}

// fused per-dst attention: one wave per node; lanes = 16 edge-slots x 4 heads
// q/k/v in fp16 (64B rows = 1 cache line per gather)
__global__ __launch_bounds__(256) void k_attn(const __half* __restrict__ q,
        const __half* __restrict__ kk, const __half* __restrict__ vv,
        const int* __restrict__ rs, const int* __restrict__ deg,
        const int* __restrict__ csr_src, float* __restrict__ attn) {
    int wid = (blockIdx.x * 256 + threadIdx.x) >> 6;
    int lane = threadIdx.x & 63;
    if (wid >= NN) return;
    int eslot = lane >> 2, head = lane & 3;
    int start = rs[wid], g = deg[wid];
    // k row slice for this head -> fp32 regs
    union HF { float4 f4; __half2 h2[4]; };
    HF ku;
    ku.f4 = *(const float4*)(kk + (size_t)wid * D + head * HD);
    float kf[HD];
    #pragma unroll
    for (int i = 0; i < 4; ++i) {
        float2 t = __half22float2(ku.h2[i]);
        kf[2 * i] = t.x; kf[2 * i + 1] = t.y;
    }
    float m = -INFINITY, l = 0.f;
    float acc[HD];
    #pragma unroll
    for (int i = 0; i < HD; ++i) acc[i] = 0.f;
    for (int base = 0; base < g; base += 16) {
        int idx = base + eslot;
        bool act = idx < g;
        int sn = act ? csr_src[start + idx] : 0;
        float s = -INFINITY;
        HF vu;
        if (act) {
            HF qu;
            qu.f4 = *(const float4*)(q + (size_t)sn * D + head * HD);
            vu.f4 = *(const float4*)(vv + (size_t)sn * D + head * HD);
            float acc_s = 0.f;
            #pragma unroll
            for (int i = 0; i < 4; ++i) {
                float2 t = __half22float2(qu.h2[i]);
                acc_s = fmaf(t.x, kf[2 * i], acc_s);
                acc_s = fmaf(t.y, kf[2 * i + 1], acc_s);
            }
            s = acc_s * 0.35355339059327376f;
        }
        float cm = s;
        #pragma unroll
        for (int off = 4; off < 64; off <<= 1)
            cm = fmaxf(cm, __shfl_xor(cm, off));
        float nm = fmaxf(m, cm);
        float scale = __expf(m - nm);
        m = nm;
        l *= scale;
        #pragma unroll
        for (int i = 0; i < HD; ++i) acc[i] *= scale;
        if (act) {
            float p = __expf(s - nm);
            l += p;
            #pragma unroll
            for (int i = 0; i < 4; ++i) {
                float2 t = __half22float2(vu.h2[i]);
                acc[2 * i] = fmaf(p, t.x, acc[2 * i]);
                acc[2 * i + 1] = fmaf(p, t.y, acc[2 * i + 1]);
            }
        }
    }
    #pragma unroll
    for (int off = 4; off < 64; off <<= 1) {
        l += __shfl_xor(l, off);
        #pragma unroll
        for (int i = 0; i < HD; ++i) acc[i] += __shfl_xor(acc[i], off);
    }
    if (eslot == 0) {
        float inv = (l > 0.f) ? 1.0f / l : 0.f;
        float* outp = attn + (size_t)wid * D + head * HD;
        #pragma unroll
        for (int i = 0; i < HD; ++i) outp[i] = acc[i] * inv;
    }
}

// h += attn @ Wo + bo
__global__ __launch_bounds__(256) void k_oproj(const float* __restrict__ attn,
        const float* __restrict__ Wo, const float* __restrict__ bo,
        float* __restrict__ h) {
    __shared__ float Ws[D * D];
    __shared__ float as[8][D];
    for (int i = threadIdx.x; i < D * D; i += 256) Ws[i] = Wo[i];
    int ln = threadIdx.x >> 5, col = threadIdx.x & 31;
    int node = blockIdx.x * 8 + ln;
    as[ln][col] = attn[(size_t)node * D + col];
    __syncthreads();
    float a = bo[col];
    #pragma unroll
    for (int i = 0; i < D; ++i) a = fmaf(as[ln][i], Ws[i * D + col], a);
    h[(size_t)node * D + col] += a;
}

// h += gelu(h @ W1 + b1) @ W2 + b2
__global__ __launch_bounds__(256) void k_ffn(const float* __restrict__ W1,
        const float* __restrict__ b1, const float* __restrict__ W2,
        const float* __restrict__ b2, float* __restrict__ h) {
    __shared__ float Ws1[D * D], Ws2[D * D];
    __shared__ float hs[8][D], ts[8][D];
    for (int i = threadIdx.x; i < D * D; i += 256) { Ws1[i] = W1[i]; Ws2[i] = W2[i]; }
    int ln = threadIdx.x >> 5, col = threadIdx.x & 31;
    int node = blockIdx.x * 8 + ln;
    float hval = h[(size_t)node * D + col];
    hs[ln][col] = hval;
    __syncthreads();
    float t = b1[col];
    #pragma unroll
    for (int i = 0; i < D; ++i) t = fmaf(hs[ln][i], Ws1[i * D + col], t);
    ts[ln][col] = gelu_f(t);
    __syncthreads();
    float o = b2[col];
    #pragma unroll
    for (int i = 0; i < D; ++i) o = fmaf(ts[ln][i], Ws2[i * D + col], o);
    h[(size_t)node * D + col] = hval + o;
}

// out = h @ W_out + b_out
__global__ void k_out(const float* __restrict__ h, const float* __restrict__ W,
        const float* __restrict__ b, float* __restrict__ out) {
    int n = blockIdx.x * blockDim.x + threadIdx.x;
    if (n >= NN) return;
    const float4* hr = (const float4*)(h + (size_t)n * D);
    float a0 = b[0], a1 = b[1];
    #pragma unroll
    for (int i = 0; i < 8; ++i) {
        float4 hv = hr[i];
        a0 += hv.x * W[(i * 4 + 0) * 2 + 0] + hv.y * W[(i * 4 + 1) * 2 + 0]
            + hv.z * W[(i * 4 + 2) * 2 + 0] + hv.w * W[(i * 4 + 3) * 2 + 0];
        a1 += hv.x * W[(i * 4 + 0) * 2 + 1] + hv.y * W[(i * 4 + 1) * 2 + 1]
            + hv.z * W[(i * 4 + 2) * 2 + 1] + hv.w * W[(i * 4 + 3) * 2 + 1];
    }
    out[n * 2 + 0] = a0;
    out[n * 2 + 1] = a1;
}

extern "C" void kernel_launch(void* const* d_in, const int* in_sizes, int n_in,
                              void* d_out, int out_size, void* d_ws, size_t ws_size,
                              hipStream_t stream) {
    const float* x     = (const float*)d_in[0];
    const int*   src   = (const int*)d_in[1];
    const int*   dst   = (const int*)d_in[2];
    const float* W_in  = (const float*)d_in[3];
    const float* b_in  = (const float*)d_in[4];
    const float* Wq    = (const float*)d_in[5];
    const float* bq    = (const float*)d_in[6];
    const float* Wk    = (const float*)d_in[7];
    const float* bk    = (const float*)d_in[8];
    const float* Wv    = (const float*)d_in[9];
    const float* bv    = (const float*)d_in[10];
    const float* Wo    = (const float*)d_in[11];
    const float* bo    = (const float*)d_in[12];
    const float* W1    = (const float*)d_in[13];
    const float* b1    = (const float*)d_in[14];
    const float* W2    = (const float*)d_in[15];
    const float* b2    = (const float*)d_in[16];
    const float* W_out = (const float*)d_in[17];
    const float* b_out = (const float*)d_in[18];
    float* out = (float*)d_out;

    char* w = (char*)d_ws;
    size_t off = 0;
    auto alloc = [&](size_t bytes) -> void* {
        void* p = w + off;
        off += (bytes + 255) & ~(size_t)255;
        return p;
    };
    float*  h    = (float*)alloc((size_t)NN * D * 4);
    __half* q    = (__half*)alloc((size_t)NN * D * 2);
    __half* kk   = (__half*)alloc((size_t)NN * D * 2);
    __half* vv   = (__half*)alloc((size_t)NN * D * 2);
    float*  attn = (float*)alloc((size_t)NN * D * 4);  // aliased as tmp during CSR build
    int* deg    = (int*)alloc((size_t)NN * 4);
    int* rs     = (int*)alloc((size_t)NN * 4);
    int* bhist  = (int*)alloc((size_t)NBKT * NBLK * 4);
    int* btot   = (int*)alloc((size_t)NBKT * 4);
    int* bbase  = (int*)alloc((size_t)(NBKT + 1) * 4);
    int* csr    = (int*)alloc((size_t)NE * 4);
    unsigned int* tmp = (unsigned int*)attn;           // NE*4 == NN*D*4 bytes
    (void)ws_size; (void)in_sizes; (void)n_in; (void)out_size;

    k_in_proj<<<NN / 8, 256, 0, stream>>>(x, W_in, b_in, h);
    k_binA<<<NBLK, 256, 0, stream>>>(dst, bhist);
    k_binB1<<<NBKT, NBLK, 0, stream>>>(bhist, btot);
    k_binB2<<<1, 512, 0, stream>>>(btot, bbase);
    k_binC<<<NBLK, 256, 0, stream>>>(src, dst, bhist, bbase, tmp);
    k_binD<<<NBKT, 256, 0, stream>>>(tmp, bbase, csr, rs, deg);

    for (int l = 0; l < 2; ++l) {
        k_qkv<<<NN / 8, 256, 0, stream>>>(h, Wq + l * D * D, bq + l * D,
                                          Wk + l * D * D, bk + l * D,
                                          Wv + l * D * D, bv + l * D, q, kk, vv);
        k_attn<<<NN / 4, 256, 0, stream>>>(q, kk, vv, rs, deg, csr, attn);
        k_oproj<<<NN / 8, 256, 0, stream>>>(attn, Wo + l * D * D, bo + l * D, h);
        k_ffn<<<NN / 8, 256, 0, stream>>>(W1 + l * D * D, b1 + l * D,
                                          W2 + l * D * D, b2 + l * D, h);
    }
    k_out<<<(NN + 255) / 256, 256, 0, stream>>>(h, W_out, b_out, out);
}